// Round 1
// 470.970 us; speedup vs baseline: 1.0094x; 1.0094x over previous
//
#include <hip/hip_runtime.h>
#include <hip/hip_bf16.h>

using bf16 = __hip_bfloat16;
typedef short bf16x8v  __attribute__((ext_vector_type(8)));
typedef float f32x16v  __attribute__((ext_vector_type(16)));

#define GLD_LDS16(g, l) __builtin_amdgcn_global_load_lds(                      \
    (const __attribute__((address_space(1))) void*)(g),                        \
    (__attribute__((address_space(3))) void*)(l), 16, 0, 0)

__device__ __forceinline__ float bflo(unsigned int u) {
  union { unsigned int i; float f; } c; c.i = u << 16; return c.f;
}
__device__ __forceinline__ float bfhi(unsigned int u) {
  union { unsigned int i; float f; } c; c.i = u & 0xffff0000u; return c.f;
}
__device__ __forceinline__ unsigned int packbf(float a, float b) {
  return (unsigned int)(__hip_bfloat16_raw(__float2bfloat16(a)).x) |
         ((unsigned int)(__hip_bfloat16_raw(__float2bfloat16(b)).x) << 16);
}
__device__ __forceinline__ unsigned short bfraw(float a) {
  return __hip_bfloat16_raw(__float2bfloat16(a)).x;
}

// ------------------------------------------------- all fp32->bf16 casts, one launch
__global__ void f2b4_all(const float* __restrict__ x,  const float* __restrict__ wk,
                         const float* __restrict__ wv, const float* __restrict__ wr,
                         const float* __restrict__ wo,
                         bf16* __restrict__ x_bf, bf16* __restrict__ wcat,
                         bf16* __restrict__ wo_bf) {
  int i = blockIdx.x * blockDim.x + threadIdx.x;
  const float* s; bf16* d; int idx;
  if (i < 6291456) { s = x; d = x_bf; idx = i; }
  else {
    int j = i - 6291456;
    int seg = j / 147456;
    idx = j - seg * 147456;
    if (seg == 0)      { s = wk; d = wcat; }
    else if (seg == 1) { s = wv; d = wcat + 589824; }
    else if (seg == 2) { s = wr; d = wcat + 1179648; }
    else               { s = wo; d = wo_bf; }
  }
  const float4 f = reinterpret_cast<const float4*>(s)[idx];
  struct B4 { bf16 a, b, c, d; };
  B4 o = { __float2bfloat16(f.x), __float2bfloat16(f.y),
           __float2bfloat16(f.z), __float2bfloat16(f.w) };
  reinterpret_cast<B4*>(d)[idx] = o;
}

// =========================================================================
// 256x256 tile, BK=64, 8 waves (2M x 4N), 8-phase schedule with counted
// vmcnt (T3+T4), setprio around MFMA clusters (T5), granule-XOR LDS swizzle.
// MFMA: v_mfma_f32_32x32x16_bf16 with SWAPPED operands (D holds 4 consecutive
// n per reg-quad -> packed epilogue). Layout math carried over verbatim from
// the verified 128^2 kernel.
//
// LDS (128 KiB): [buf0.A | buf0.B | buf1.A | buf1.B], each 256x64 bf16.
// Staging: half-tile (128 rows x 64 k) per phase = 2 global_load_lds/thread.
// Stage->region schedule (race-free; each overwrite is barrier-separated
// from the region's last read):
//   P0: buf1.A h0 (tile 2t+1)   P4: buf0.A h0 (tile 2t+2)
//   P1: buf1.A h1               P5: buf0.A h1
//   P2: buf0.B h0 (tile 2t+2)   P6: buf1.B h0 (tile 2t+3)
//   P3: buf0.B h1, vmcnt(4)     P7: buf1.B h1, vmcnt(4)
// Last iteration: P2..P7 stages skipped; P3 waits vmcnt(0).
// =========================================================================

__device__ __forceinline__ void stg(bf16* dst, const bf16* src, int kt,
                                    const int srow[2], const int scol[2],
                                    int tid) {
#pragma unroll
  for (int q = 0; q < 2; ++q)
    GLD_LDS16(src + (size_t)srow[q] * 768 + kt * 64 + scol[q],
              dst + (size_t)(tid + q * 512) * 8);
}

__device__ __forceinline__ void lda2(bf16x8v av[2][4], const bf16* bufA,
                                     int aBase, int ih, int hi, int sx) {
#pragma unroll
  for (int ks = 0; ks < 4; ++ks)
#pragma unroll
    for (int ii = 0; ii < 2; ++ii)
      av[ii][ks] = *(const bf16x8v*)(bufA + aBase + (ih * 2 + ii) * 2048 +
                                     (((ks * 2 + hi) ^ sx) * 8));
}

__device__ __forceinline__ void ldb1(bf16x8v bv[4], const bf16* bufB,
                                     int bBase, int j, int hi, int sx) {
#pragma unroll
  for (int ks = 0; ks < 4; ++ks)
    bv[ks] = *(const bf16x8v*)(bufB + bBase + j * 2048 +
                               (((ks * 2 + hi) ^ sx) * 8));
}

__device__ __forceinline__ void mm8(f32x16v acc[4][2], const bf16x8v av[2][4],
                                    const bf16x8v bv[4], int ih, int j) {
#pragma unroll
  for (int ks = 0; ks < 4; ++ks)
#pragma unroll
    for (int ii = 0; ii < 2; ++ii)
      acc[ih * 2 + ii][j] = __builtin_amdgcn_mfma_f32_32x32x16_bf16(
          bv[ks], av[ii][ks], acc[ih * 2 + ii][j], 0, 0, 0);
}

#define PH_SYNC_PRE()                                                          \
  __builtin_amdgcn_s_barrier();                                                \
  asm volatile("s_waitcnt lgkmcnt(0)" ::: "memory");                           \
  __builtin_amdgcn_s_setprio(1);

#define PH_SYNC_POST()                                                         \
  __builtin_amdgcn_s_setprio(0);                                               \
  __builtin_amdgcn_s_barrier();

__device__ __forceinline__ void gemm256_core(
    const bf16* __restrict__ A, const bf16* __restrict__ W,
    bf16* lds, size_t m0, size_t n0, int tid, f32x16v acc[4][2])
{
  bf16* const A0 = lds;                 // buf0.A  256x64
  bf16* const B0 = lds + 16384;         // buf0.B
  bf16* const A1 = lds + 32768;         // buf1.A
  bf16* const B1 = lds + 49152;         // buf1.B

  const int lane = tid & 63, wave = tid >> 6;
  const int l31 = lane & 31, hi = lane >> 5;
  const int wm = wave >> 2, wn = wave & 3;
  const int sx = l31 & 7;
  const int aBase = (wm * 128 + l31) * 64;
  const int bBase = (wn * 64 + l31) * 64;

  int srow[2], scol[2];
#pragma unroll
  for (int q = 0; q < 2; ++q) {
    const int s = tid + q * 512;
    srow[q] = s >> 3;
    scol[q] = ((s & 7) ^ (srow[q] & 7)) * 8;
  }
  const bf16* aS0 = A + m0 * 768;
  const bf16* aS1 = A + (m0 + 128) * 768;
  const bf16* bS0 = W + n0 * 768;
  const bf16* bS1 = W + (n0 + 128) * 768;

  bf16x8v av[2][4], bv[2][4];

#pragma unroll
  for (int i = 0; i < 4; ++i)
#pragma unroll
    for (int j = 0; j < 2; ++j)
#pragma unroll
      for (int r = 0; r < 16; ++r) acc[i][j][r] = 0.0f;

  // ---- prologue: tile0 -> buf0 (A+B), tile1.B -> buf1.B (6 halves)
  stg(A0,        aS0, 0, srow, scol, tid);
  stg(A0 + 8192, aS1, 0, srow, scol, tid);
  stg(B0,        bS0, 0, srow, scol, tid);
  stg(B0 + 8192, bS1, 0, srow, scol, tid);
  stg(B1,        bS0, 1, srow, scol, tid);
  stg(B1 + 8192, bS1, 1, srow, scol, tid);
  asm volatile("s_waitcnt vmcnt(4)" ::: "memory");   // buf0 fully landed
  __builtin_amdgcn_s_barrier();

  for (int it = 0; it < 6; ++it) {
    const bool last = (it == 5);
    const int ta = 2 * it + 1;   // buf1.A target tile
    const int tb = 2 * it + 2;   // buf0.B / buf0.A target tile
    const int tc = 2 * it + 3;   // buf1.B target tile

    // ---- P0: read buf0 A(i0,i1)+B(j0); stage buf1.A h0; mfma (ih0,j0)
    lda2(av, A0, aBase, 0, hi, sx);
    ldb1(bv[0], B0, bBase, 0, hi, sx);
    stg(A1, aS0, ta, srow, scol, tid);
    PH_SYNC_PRE(); mm8(acc, av, bv[0], 0, 0); PH_SYNC_POST();

    // ---- P1: read buf0 B(j1); stage buf1.A h1; mfma (ih0,j1)
    ldb1(bv[1], B0, bBase, 1, hi, sx);
    stg(A1 + 8192, aS1, ta, srow, scol, tid);
    PH_SYNC_PRE(); mm8(acc, av, bv[1], 0, 1); PH_SYNC_POST();

    // ---- P2: read buf0 A(i2,i3); stage buf0.B h0 (tile tb); mfma (ih1,j0)
    lda2(av, A0, aBase, 1, hi, sx);
    if (!last) stg(B0, bS0, tb, srow, scol, tid);
    PH_SYNC_PRE(); mm8(acc, av, bv[0], 1, 0); PH_SYNC_POST();

    // ---- P3: stage buf0.B h1; mfma (ih1,j1); counted vmcnt -> buf1 ready
    if (!last) stg(B0 + 8192, bS1, tb, srow, scol, tid);
    __builtin_amdgcn_s_barrier();
    __builtin_amdgcn_s_setprio(1);
    mm8(acc, av, bv[1], 1, 1);
    __builtin_amdgcn_s_setprio(0);
    if (last) asm volatile("s_waitcnt vmcnt(0)" ::: "memory");
    else      asm volatile("s_waitcnt vmcnt(4)" ::: "memory");
    __builtin_amdgcn_s_barrier();

    // ---- P4: read buf1 A(i0,i1)+B(j0); stage buf0.A h0; mfma (ih0,j0)
    lda2(av, A1, aBase, 0, hi, sx);
    ldb1(bv[0], B1, bBase, 0, hi, sx);
    if (!last) stg(A0, aS0, tb, srow, scol, tid);
    PH_SYNC_PRE(); mm8(acc, av, bv[0], 0, 0); PH_SYNC_POST();

    // ---- P5: read buf1 B(j1); stage buf0.A h1; mfma (ih0,j1)
    ldb1(bv[1], B1, bBase, 1, hi, sx);
    if (!last) stg(A0 + 8192, aS1, tb, srow, scol, tid);
    PH_SYNC_PRE(); mm8(acc, av, bv[1], 0, 1); PH_SYNC_POST();

    // ---- P6: read buf1 A(i2,i3); stage buf1.B h0 (tile tc); mfma (ih1,j0)
    lda2(av, A1, aBase, 1, hi, sx);
    if (!last) stg(B1, bS0, tc, srow, scol, tid);
    PH_SYNC_PRE(); mm8(acc, av, bv[0], 1, 0); PH_SYNC_POST();

    // ---- P7: stage buf1.B h1; mfma (ih1,j1); counted vmcnt -> buf0 ready
    if (!last) stg(B1 + 8192, bS1, tc, srow, scol, tid);
    __builtin_amdgcn_s_barrier();
    __builtin_amdgcn_s_setprio(1);
    mm8(acc, av, bv[1], 1, 1);
    __builtin_amdgcn_s_setprio(0);
    if (!last) {
      asm volatile("s_waitcnt vmcnt(4)" ::: "memory");
      __builtin_amdgcn_s_barrier();
    }
  }
}

// Epilogue mapping (swapped operands, verified on the 128^2 kernel):
//   C row (m) = m0 + wm*128 + 32*i + l31
//   C col (n) = n0 + wn*64 + 32*j + (reg&3) + 8*(reg>>2) + 4*hi

// Fused K/V/R GEMM: M=32768, N=2304, K=768. 1152 blocks = 128 m x 9 n.
__global__ __launch_bounds__(512, 2) void gemm_kvr(
    const bf16* __restrict__ A, const bf16* __restrict__ Wcat,
    bf16* __restrict__ Kb, bf16* __restrict__ Vb, bf16* __restrict__ SRb)
{
  __shared__ __align__(16) bf16 lds[65536];   // 128 KiB
  const int tid = threadIdx.x;
  const int bid = blockIdx.x;
  const int tl  = (bid & 7) * 144 + (bid >> 3);   // XCD swizzle (1152%8==0)
  const int mt  = tl / 9;
  const int ntl = tl - mt * 9;
  const size_t m0 = (size_t)mt * 256;
  const int n0 = ntl * 256;

  f32x16v acc[4][2];
  gemm256_core(A, Wcat, lds, m0, (size_t)n0, tid, acc);

  const int seg   = (n0 >= 1536) ? 2 : (n0 >= 768) ? 1 : 0;
  const int ncol0 = n0 - seg * 768;
  bf16* __restrict__ dst = (seg == 0) ? Kb : (seg == 1) ? Vb : SRb;
  const int lane = tid & 63, wave = tid >> 6;
  const int l31 = lane & 31, hi = lane >> 5;
  const int wm = wave >> 2, wn = wave & 3;
#pragma unroll
  for (int i = 0; i < 4; ++i) {
    const size_t mrow = m0 + wm * 128 + 32 * i + l31;
#pragma unroll
    for (int j = 0; j < 2; ++j) {
      const int nb = ncol0 + wn * 64 + 32 * j + 4 * hi;
#pragma unroll
      for (int rr = 0; rr < 4; ++rr) {
        float v0 = acc[i][j][4 * rr + 0], v1 = acc[i][j][4 * rr + 1];
        float v2 = acc[i][j][4 * rr + 2], v3 = acc[i][j][4 * rr + 3];
        if (seg == 2) {
          v0 = 1.0f / (1.0f + __expf(-v0)); v1 = 1.0f / (1.0f + __expf(-v1));
          v2 = 1.0f / (1.0f + __expf(-v2)); v3 = 1.0f / (1.0f + __expf(-v3));
        }
        ushort4 pk = { bfraw(v0), bfraw(v1), bfraw(v2), bfraw(v3) };
        *(ushort4*)&dst[mrow * 768 + nb + 8 * rr] = pk;
      }
    }
  }
}

// Output GEMM: M=32768, N=768, K=768, fp32 out. 384 blocks = 128 m x 3 n.
__global__ __launch_bounds__(512, 2) void gemm_out(
    const bf16* __restrict__ A, const bf16* __restrict__ W,
    float* __restrict__ out)
{
  __shared__ __align__(16) bf16 lds[65536];
  const int tid = threadIdx.x;
  const int bid = blockIdx.x;
  const int tl  = (bid & 7) * 48 + (bid >> 3);    // XCD swizzle (384%8==0)
  const int mt  = tl / 3;
  const int ntl = tl - mt * 3;
  const size_t m0 = (size_t)mt * 256;
  const int n0 = ntl * 256;

  f32x16v acc[4][2];
  gemm256_core(A, W, lds, m0, (size_t)n0, tid, acc);

  const int lane = tid & 63, wave = tid >> 6;
  const int l31 = lane & 31, hi = lane >> 5;
  const int wm = wave >> 2, wn = wave & 3;
#pragma unroll
  for (int i = 0; i < 4; ++i) {
    const size_t mrow = m0 + wm * 128 + 32 * i + l31;
#pragma unroll
    for (int j = 0; j < 2; ++j) {
      const int nb = n0 + wn * 64 + 32 * j + 4 * hi;
#pragma unroll
      for (int rr = 0; rr < 4; ++rr) {
        float4 pk = { acc[i][j][4 * rr + 0], acc[i][j][4 * rr + 1],
                      acc[i][j][4 * rr + 2], acc[i][j][4 * rr + 3] };
        *(float4*)&out[mrow * 768 + nb + 8 * rr] = pk;
      }
    }
  }
}

// ------------------------------------------------------------ WKV chunk scan
// G=128 chunks of L=32. 4 channels/thread. State math fp32.
__global__ void wkv_phaseA(const bf16* __restrict__ K, const bf16* __restrict__ V,
                           const float* __restrict__ sd,
                           float* __restrict__ sA, float* __restrict__ sB, float* __restrict__ sP)
{
  const int idx = blockIdx.x * 256 + threadIdx.x;
  const int c4 = idx % 192;
  const int bg = idx / 192;
  const int g  = bg & 127;
  const int b  = bg >> 7;
  const int c0 = c4 * 4;
  float w[4], aa[4], bb[4], pp[4];
#pragma unroll
  for (int e = 0; e < 4; ++e) {
    w[e] = sd[c0 + e] * (1.0f / 4096.0f);
    aa[e] = 0.f; bb[e] = 0.f; pp[e] = -1e38f;
  }
  const size_t base = ((size_t)b * 4096 + (size_t)g * 32) * 768 + c0;
  const uint2* Kp = (const uint2*)(K + base);
  const uint2* Vp = (const uint2*)(V + base);
#pragma unroll 4
  for (int t = 0; t < 32; ++t) {
    const uint2 ku = Kp[(size_t)t * 192];
    const uint2 vu = Vp[(size_t)t * 192];
    const float kc[4] = { bflo(ku.x), bfhi(ku.x), bflo(ku.y), bfhi(ku.y) };
    const float vc[4] = { bflo(vu.x), bfhi(vu.x), bflo(vu.y), bfhi(vu.y) };
#pragma unroll
    for (int e = 0; e < 4; ++e) {
      const float ww2 = w[e] + pp[e];
      const float p2  = fmaxf(ww2, kc[e]);
      const float e1b = __expf(ww2 - p2);
      const float e2b = __expf(kc[e] - p2);
      aa[e] = e1b * aa[e] + e2b * vc[e];
      bb[e] = e1b * bb[e] + e2b;
      pp[e] = p2;
    }
  }
  const int o = g * 6144 + b * 768 + c0;
#pragma unroll
  for (int e = 0; e < 4; ++e) { sA[o + e] = aa[e]; sB[o + e] = bb[e]; sP[o + e] = pp[e]; }
}

__global__ void wkv_phaseB(const float* __restrict__ sA, const float* __restrict__ sB,
                           const float* __restrict__ sP,
                           float* __restrict__ iA, float* __restrict__ iB, float* __restrict__ iP,
                           const float* __restrict__ sd)
{
  const int bc = blockIdx.x * 256 + threadIdx.x;    // B*C = 6144
  const int c  = bc % 768;
  const float Lw = 32.0f * (sd[c] * (1.0f / 4096.0f));
  float aa = 0.f, bb = 0.f, pp = -1e38f;
  for (int g = 0; g < 128; ++g) {
    const int o = g * 6144 + bc;
    iA[o] = aa; iB[o] = bb; iP[o] = pp;             // state BEFORE chunk g
    const float la = sA[o], lb = sB[o], lp = sP[o];
    const float pd = pp + Lw;
    const float pn = fmaxf(pd, lp);
    const float e0 = __expf(pd - pn);
    const float e1 = __expf(lp - pn);
    aa = e0 * aa + e1 * la;
    bb = e0 * bb + e1 * lb;
    pp = pn;
  }
}

__global__ void wkv_phaseC(const bf16* __restrict__ K, const bf16* __restrict__ V,
                           const bf16* __restrict__ SR,
                           const float* __restrict__ iA, const float* __restrict__ iB,
                           const float* __restrict__ iP,
                           const float* __restrict__ sd, const float* __restrict__ sf,
                           bf16* __restrict__ RY)
{
  const int idx = blockIdx.x * 256 + threadIdx.x;
  const int c4 = idx % 192;
  const int bg = idx / 192;
  const int g  = bg & 127;
  const int b  = bg >> 7;
  const int c0 = c4 * 4;
  const int o = g * 6144 + b * 768 + c0;
  float w[4], u[4], aa[4], bb[4], pp[4];
#pragma unroll
  for (int e = 0; e < 4; ++e) {
    w[e] = sd[c0 + e] * (1.0f / 4096.0f);
    u[e] = sf[c0 + e] * (1.0f / 4096.0f);
    aa[e] = iA[o + e]; bb[e] = iB[o + e]; pp[e] = iP[o + e];
  }
  const size_t base = ((size_t)b * 4096 + (size_t)g * 32) * 768 + c0;
  const uint2* Kp = (const uint2*)(K + base);
  const uint2* Vp = (const uint2*)(V + base);
  const uint2* Sp = (const uint2*)(SR + base);
  uint2* Rp = (uint2*)(RY + base);
#pragma unroll 4
  for (int t = 0; t < 32; ++t) {
    const uint2 ku = Kp[(size_t)t * 192];
    const uint2 vu = Vp[(size_t)t * 192];
    const uint2 su = Sp[(size_t)t * 192];
    const float kc[4] = { bflo(ku.x), bfhi(ku.x), bflo(ku.y), bfhi(ku.y) };
    const float vc[4] = { bflo(vu.x), bfhi(vu.x), bflo(vu.y), bfhi(vu.y) };
    const float sc[4] = { bflo(su.x), bfhi(su.x), bflo(su.y), bfhi(su.y) };
    float y[4];
#pragma unroll
    for (int e = 0; e < 4; ++e) {
      const float ww = u[e] + kc[e];
      const float p  = fmaxf(pp[e], ww);
      const float e1 = __expf(pp[e] - p);
      const float e2 = __expf(ww - p);
      y[e] = (e1 * aa[e] + e2 * vc[e]) / (e1 * bb[e] + e2) * sc[e];
      const float ww2 = w[e] + pp[e];
      const float p2  = fmaxf(ww2, kc[e]);
      const float e1b = __expf(ww2 - p2);
      const float e2b = __expf(kc[e] - p2);
      aa[e] = e1b * aa[e] + e2b * vc[e];
      bb[e] = e1b * bb[e] + e2b;
      pp[e] = p2;
    }
    uint2 r; r.x = packbf(y[0], y[1]); r.y = packbf(y[2], y[3]);
    Rp[(size_t)t * 192] = r;
  }
}

// ---------------------------------------------------------------------------
extern "C" void kernel_launch(void* const* d_in, const int* in_sizes, int n_in,
                              void* d_out, int out_size, void* d_ws, size_t ws_size,
                              hipStream_t stream)
{
  const float* x  = (const float*)d_in[0];
  const float* wk = (const float*)d_in[1];
  const float* wv = (const float*)d_in[2];
  const float* wr = (const float*)d_in[3];
  const float* wo = (const float*)d_in[4];
  const float* sd = (const float*)d_in[5];
  const float* sf = (const float*)d_in[6];
  float* out = (float*)d_out;

  char* ws = (char*)d_ws;
  bf16*  x_bf  = (bf16*) (ws + 0);            // 25165824 * 2
  bf16*  wcat  = (bf16*) (ws + 50331648);     // 2304x768 bf16
  bf16*  wo_bf = (bf16*) (ws + 53870592);
  bf16*  Kb    = (bf16*) (ws + 55050240);     // 25165824 * 2 each
  bf16*  Vb    = (bf16*) (ws + 105381888);
  bf16*  SRb   = (bf16*) (ws + 155713536);
  float* sumA  = (float*)(ws + 206045184);    // 128*6144 floats (3 MB) each
  float* sumB  = (float*)(ws + 209190912);
  float* sumP  = (float*)(ws + 212336640);
  float* iniA  = (float*)(ws + 215482368);
  float* iniB  = (float*)(ws + 218628096);
  float* iniP  = (float*)(ws + 221773824);
  bf16*  ry_bf = x_bf;                        // x dead after gemm_kvr -> alias

  f2b4_all<<<26880, 256, 0, stream>>>(x, wk, wv, wr, wo, x_bf, wcat, wo_bf);

  gemm_kvr<<<1152, 512, 0, stream>>>(x_bf, wcat, Kb, Vb, SRb);

  wkv_phaseA<<<768, 256, 0, stream>>>(Kb, Vb, sd, sumA, sumB, sumP);
  wkv_phaseB<<<24,  256, 0, stream>>>(sumA, sumB, sumP, iniA, iniB, iniP, sd);
  wkv_phaseC<<<768, 256, 0, stream>>>(Kb, Vb, SRb, iniA, iniB, iniP, sd, sf, ry_bf);

  gemm_out<<<384, 512, 0, stream>>>(ry_bf, wo_bf, out);
}